// Round 5
// baseline (726.405 us; speedup 1.0000x reference)
//
#include <hip/hip_runtime.h>
#include <math.h>
#include <cstddef>

// Problem constants
#define BB 2
#define TT 2048
#define CC 2048
#define HH 16
#define HD 128
#define MM (BB * TT)   // 4096 tokens
#define QKV_N 6144
#define BK 32

typedef __attribute__((ext_vector_type(8))) short short8;
typedef __attribute__((ext_vector_type(4))) float f32x4;

__device__ __forceinline__ unsigned short f2bf(float f) {
    union { float f; unsigned int u; } v; v.f = f;
    unsigned int r = v.u + 0x7FFFu + ((v.u >> 16) & 1u);  // RNE
    return (unsigned short)(r >> 16);
}
__device__ __forceinline__ float bf2f(unsigned short s) {
    union { unsigned int u; float f; } v; v.u = ((unsigned int)s) << 16;
    return v.f;
}
__device__ __forceinline__ void gload16(const void* g, void* l) {
    __builtin_amdgcn_global_load_lds(
        (const __attribute__((address_space(1))) unsigned int*)g,
        (__attribute__((address_space(3))) unsigned int*)l, 16, 0, 0);
}

// ---------------------------------------------------------------------------
// K1: gating. One block per token. fp32 (argmax ties must match np).
// ---------------------------------------------------------------------------
__global__ __launch_bounds__(256) void gate_kernel(const float* __restrict__ x,
                                                   const float* __restrict__ Wg,
                                                   int* __restrict__ idxbuf,
                                                   float* __restrict__ top1buf) {
    int m = blockIdx.x;
    int tid = threadIdx.x;
    int h = tid >> 4;
    int j = tid & 15;
    const float4* xr = (const float4*)(x + (size_t)m * CC);
    const float4* wr = (const float4*)(Wg + (size_t)h * CC);
    float acc = 0.f;
#pragma unroll 8
    for (int i = 0; i < CC / 4; i += 16) {
        float4 a = xr[i + j];
        float4 b = wr[i + j];
        acc += a.x * b.x + a.y * b.y + a.z * b.z + a.w * b.w;
    }
    for (int off = 8; off > 0; off >>= 1) acc += __shfl_down(acc, off, 16);
    __shared__ float logits[HH];
    if (j == 0) logits[h] = acc;
    __syncthreads();
    if (tid == 0) {
        float zmax = logits[0];
        int best = 0;
        for (int i = 1; i < HH; i++) {
            if (logits[i] > zmax) { zmax = logits[i]; best = i; }
        }
        float s = 0.f;
        for (int i = 0; i < HH; i++) s += expf(logits[i] - zmax);
        idxbuf[m] = best;
        top1buf[m] = 1.0f / s;
    }
}

// ---------------------------------------------------------------------------
// K2: fp32 -> bf16 convert (8 elems/thread, 16B stores).
// ---------------------------------------------------------------------------
__global__ __launch_bounds__(256) void convert_bf16(const float* __restrict__ src,
                                                    unsigned short* __restrict__ dst,
                                                    int n8) {
    int i = blockIdx.x * 256 + threadIdx.x;
    if (i >= n8) return;
    const float4* s4 = (const float4*)src;
    float4 a = s4[i * 2], b = s4[i * 2 + 1];
    union { unsigned short s[8]; uint4 u; } pk;
    pk.s[0] = f2bf(a.x); pk.s[1] = f2bf(a.y); pk.s[2] = f2bf(a.z); pk.s[3] = f2bf(a.w);
    pk.s[4] = f2bf(b.x); pk.s[5] = f2bf(b.y); pk.s[6] = f2bf(b.z); pk.s[7] = f2bf(b.w);
    ((uint4*)dst)[i] = pk.u;
}

// ---------------------------------------------------------------------------
// K3: qkv = xb @ wbT, bf16 MFMA GEMM (m97 structure).
// ---------------------------------------------------------------------------
__global__ __launch_bounds__(256) void qkv_gemm(const unsigned short* __restrict__ A,  // [M][2048] bf16
                                                const unsigned short* __restrict__ Bm, // [N][2048] bf16
                                                unsigned short* __restrict__ C) {      // [M][6144] bf16
    __shared__ unsigned short As[128 * BK];  // 8 KB
    __shared__ unsigned short Bs[128 * BK];  // 8 KB
    int tid = threadIdx.x;
    int wave = tid >> 6, lane = tid & 63;
    int l = lane & 15, g = lane >> 4;
    int m0 = blockIdx.y * 128, n0 = blockIdx.x * 128;
    int wr = wave >> 1, wc = wave & 1;

    f32x4 acc[4][4];
#pragma unroll
    for (int i = 0; i < 4; i++)
#pragma unroll
        for (int j = 0; j < 4; j++) acc[i][j] = (f32x4){0.f, 0.f, 0.f, 0.f};

    int srow = lane >> 2;
    int scol = (lane & 3) * 8;
    const unsigned short* aB0 = A + (size_t)(m0 + wave * 32 + srow) * 2048 + scol;
    const unsigned short* bB0 = Bm + (size_t)(n0 + wave * 32 + srow) * 2048 + scol;
    unsigned short* aL0 = &As[wave * 1024];
    unsigned short* bL0 = &Bs[wave * 1024];

    for (int k0 = 0; k0 < 2048; k0 += BK) {
        __syncthreads();
        gload16(aB0 + k0, aL0);
        gload16(aB0 + k0 + (size_t)16 * 2048, aL0 + 512);
        gload16(bB0 + k0, bL0);
        gload16(bB0 + k0 + (size_t)16 * 2048, bL0 + 512);
        __syncthreads();
        short8 af[4], bf[4];
#pragma unroll
        for (int i = 0; i < 4; i++)
            af[i] = *(const short8*)&As[(wr * 64 + i * 16 + l) * BK + g * 8];
#pragma unroll
        for (int j = 0; j < 4; j++)
            bf[j] = *(const short8*)&Bs[(wc * 64 + j * 16 + l) * BK + g * 8];
#pragma unroll
        for (int i = 0; i < 4; i++)
#pragma unroll
            for (int j = 0; j < 4; j++)
                acc[i][j] = __builtin_amdgcn_mfma_f32_16x16x32_bf16(af[i], bf[j], acc[i][j], 0, 0, 0);
    }

    const float qscale = 0.08838834764831845f;  // 1/sqrt(128)
#pragma unroll
    for (int j = 0; j < 4; j++) {
        int col = n0 + wc * 64 + j * 16 + l;
        float s = (col < 2048) ? qscale : 1.0f;
#pragma unroll
        for (int i = 0; i < 4; i++) {
            int row = m0 + wr * 64 + i * 16 + g * 4;
#pragma unroll
            for (int r = 0; r < 4; r++)
                C[(size_t)(row + r) * QKV_N + col] = f2bf(acc[i][j][r] * s);
        }
    }
}

// ---------------------------------------------------------------------------
// K4: gather selected head's k/v from qkv buffer.
// ---------------------------------------------------------------------------
__global__ __launch_bounds__(256) void kv_gather2(const unsigned short* __restrict__ qkv,
                                                  const int* __restrict__ idxb,
                                                  const float* __restrict__ top1,
                                                  unsigned short* __restrict__ kshB,
                                                  unsigned short* __restrict__ vshT) {
    __shared__ unsigned short Vs[64][136];
    int m0 = blockIdx.x * 64;
    int tid = threadIdx.x;
    int tok = tid >> 2;
    int c4 = tid & 3;
    int m = m0 + tok;
    int hs = idxb[m];
    float tv = top1[m];
    const uint4* krow = (const uint4*)(qkv + (size_t)m * QKV_N + 2048 + hs * 128);
    const uint4* vrow = (const uint4*)(qkv + (size_t)m * QKV_N + 4096 + hs * 128);
    uint4* kdst = (uint4*)(kshB + (size_t)m * HD);
#pragma unroll
    for (int u = 0; u < 4; u++) kdst[c4 * 4 + u] = krow[c4 * 4 + u];
#pragma unroll
    for (int u = 0; u < 4; u++) {
        uint4 d = vrow[c4 * 4 + u];
        unsigned short* ss = (unsigned short*)&d;
        union { unsigned short s[8]; uint4 u4; } pk;
#pragma unroll
        for (int e = 0; e < 8; e++) pk.s[e] = f2bf(bf2f(ss[e]) * tv);
        *(uint4*)&Vs[tok][(c4 * 4 + u) * 8] = pk.u4;
    }
    __syncthreads();
    int d = tid >> 1, half = tid & 1;
#pragma unroll
    for (int u = 0; u < 4; u++) {
        union { unsigned short s[8]; uint4 u4; } pk;
#pragma unroll
        for (int e = 0; e < 8; e++) pk.s[e] = Vs[half * 32 + u * 8 + e][d];
        *(uint4*)(vshT + (size_t)d * MM + m0 + half * 32 + u * 8) = pk.u4;
    }
}

// ---------------------------------------------------------------------------
// K5: MFMA bf16 flash attention, wave-independent (NO barriers, NO block
// staging). One wave = one 16-row q-tile. K/V fragments loaded directly from
// global (L2-hot: shared across 16 heads). Fixed-shift softmax exp(s-30);
// row-sum via ones-column MFMA. LDS = per-wave Ps round-trip only.
// ---------------------------------------------------------------------------
__global__ __launch_bounds__(256) void attn_mfma(const unsigned short* __restrict__ qb,   // [M][6144] bf16, q pre-scaled
                                                 const unsigned short* __restrict__ kb,   // [M][128] bf16
                                                 const unsigned short* __restrict__ vtb,  // [128][M] bf16
                                                 float* __restrict__ y) {                 // [M][2048] fp32
    __shared__ unsigned short Ps[4][16][72];   // 9216 B, per-wave

    int tid = threadIdx.x;
    int wave = tid >> 6;
    int lane = tid & 63;
    int l = lane & 15;
    int g = lane >> 4;

    int flat = blockIdx.x * 4 + wave;      // 4096 waves total
    int qq = 127 - (flat & 127);           // 16-row q-tile index, longest first
    int bh = flat >> 7;
    int h = bh & 15;
    int b = bh >> 4;
    int q0 = qq * 16;
    int nch = (qq >> 2) + 1;               // number of 64-key chunks

    // Q a-frags (bf16, pre-scaled), once per wave.
    short8 qf[4];
    {
        const unsigned short* qrowp = qb + (size_t)(b * TT + q0 + l) * QKV_N + h * HD;
#pragma unroll
        for (int kc = 0; kc < 4; kc++)
            qf[kc] = *(const short8*)(qrowp + kc * 32 + g * 8);
    }

    // ones-column B-frag: B[n][k] = (n==0) ? 1 : 0
    short8 onesf;
    {
        short v = (l == 0) ? (short)0x3F80 : (short)0;
#pragma unroll
        for (int e = 0; e < 8; e++) onesf[e] = v;
    }

    f32x4 o[8];
#pragma unroll
    for (int n = 0; n < 8; n++) o[n] = (f32x4){0.f, 0.f, 0.f, 0.f};
    f32x4 o8 = (f32x4){0.f, 0.f, 0.f, 0.f};   // row-sum accumulator (col 0)

    const unsigned short* kbase = kb + (size_t)b * TT * HD;
    const unsigned short* vbase = vtb + (size_t)b * TT;
    int rbase = q0 + g * 4;

    for (int c = 0; c < nch; c++) {
        int kc0 = c * 64;
        // S = Q K^T : B-frags straight from global (row = key, 16B/lane)
        f32x4 st[4];
#pragma unroll
        for (int t = 0; t < 4; t++) {
            f32x4 acc = (f32x4){0.f, 0.f, 0.f, 0.f};
#pragma unroll
            for (int kc = 0; kc < 4; kc++) {
                short8 bfr = *(const short8*)(kbase + (size_t)(kc0 + t * 16 + l) * HD + kc * 32 + g * 8);
                acc = __builtin_amdgcn_mfma_f32_16x16x32_bf16(qf[kc], bfr, acc, 0, 0, 0);
            }
            st[t] = acc;
        }
        if (c == nch - 1) {  // diagonal chunk: causal mask (wave-uniform branch)
#pragma unroll
            for (int t = 0; t < 4; t++) {
                int key = kc0 + t * 16 + l;
#pragma unroll
                for (int i = 0; i < 4; i++)
                    if (key > rbase + i) st[t][i] = -1e30f;
            }
        }
        // p = exp(s - 30), straight to LDS in A-layout (per-wave, no barrier)
#pragma unroll
        for (int t = 0; t < 4; t++) {
#pragma unroll
            for (int i = 0; i < 4; i++) {
                float p = __expf(st[t][i] - 30.f);
                Ps[wave][g * 4 + i][t * 16 + l] = f2bf(p);
            }
        }
        // O += P V ; l += P·ones. V frags straight from global (transposed src).
#pragma unroll
        for (int kc2 = 0; kc2 < 2; kc2++) {
            short8 pf = *(const short8*)&Ps[wave][l][kc2 * 32 + g * 8];
#pragma unroll
            for (int n = 0; n < 8; n++) {
                short8 vf = *(const short8*)(vbase + (size_t)(n * 16 + l) * MM + kc0 + kc2 * 32 + g * 8);
                o[n] = __builtin_amdgcn_mfma_f32_16x16x32_bf16(pf, vf, o[n], 0, 0, 0);
            }
            o8 = __builtin_amdgcn_mfma_f32_16x16x32_bf16(pf, onesf, o8, 0, 0, 0);
        }
    }
    // l for row g*4+i sits in lane (g*16, reg i); broadcast across the 16 lanes
    float inv[4];
#pragma unroll
    for (int i = 0; i < 4; i++) {
        float lv = __shfl(o8[i], lane & 48);
        inv[i] = 1.f / lv;
    }
#pragma unroll
    for (int n = 0; n < 8; n++) {
#pragma unroll
        for (int i = 0; i < 4; i++) {
            y[(size_t)(b * TT + q0 + g * 4 + i) * CC + h * HD + n * 16 + l] =
                o[n][i] * inv[i];
        }
    }
}

// ---------------------------------------------------------------------------
// Launcher. Workspace (~94.5 MB).
// ---------------------------------------------------------------------------
extern "C" void kernel_launch(void* const* d_in, const int* in_sizes, int n_in,
                              void* d_out, int out_size, void* d_ws, size_t ws_size,
                              hipStream_t stream) {
    (void)in_sizes; (void)n_in; (void)out_size; (void)ws_size;
    const float* x    = (const float*)d_in[0];
    const float* Wg   = (const float*)d_in[1];
    const float* Wqkv = (const float*)d_in[2];
    float* y = (float*)d_out;

    unsigned short* xb   = (unsigned short*)d_ws;
    unsigned short* wb   = xb + (size_t)MM * CC;
    unsigned short* qkvB = wb + (size_t)QKV_N * CC;
    unsigned short* kshB = qkvB + (size_t)MM * QKV_N;
    unsigned short* vshT = kshB + (size_t)MM * HD;
    float* top1 = (float*)(vshT + (size_t)HD * MM);
    int*   idxb = (int*)(top1 + MM);

    gate_kernel<<<MM, 256, 0, stream>>>(x, Wg, idxb, top1);
    convert_bf16<<<(MM * CC / 8 + 255) / 256, 256, 0, stream>>>(x, xb, MM * CC / 8);
    convert_bf16<<<(QKV_N * CC / 8 + 255) / 256, 256, 0, stream>>>(Wqkv, wb, QKV_N * CC / 8);
    qkv_gemm<<<dim3(QKV_N / 128, MM / 128), 256, 0, stream>>>(xb, wb, qkvB);
    kv_gather2<<<MM / 64, 256, 0, stream>>>(qkvB, idxb, top1, kshB, vshT);
    attn_mfma<<<(4096 / 4), 256, 0, stream>>>(qkvB, kshB, vshT, y);
}

// Round 6
// 401.090 us; speedup vs baseline: 1.8111x; 1.8111x over previous
//
#include <hip/hip_runtime.h>
#include <math.h>
#include <cstddef>

// Problem constants
#define BB 2
#define TT 2048
#define CC 2048
#define HH 16
#define HD 128
#define MM (BB * TT)   // 4096 tokens
#define QKV_N 6144
#define BK 32

typedef __attribute__((ext_vector_type(8))) short short8;
typedef __attribute__((ext_vector_type(4))) float f32x4;

__device__ __forceinline__ unsigned short f2bf(float f) {
    union { float f; unsigned int u; } v; v.f = f;
    unsigned int r = v.u + 0x7FFFu + ((v.u >> 16) & 1u);  // RNE
    return (unsigned short)(r >> 16);
}
__device__ __forceinline__ float bf2f(unsigned short s) {
    union { unsigned int u; float f; } v; v.u = ((unsigned int)s) << 16;
    return v.f;
}
__device__ __forceinline__ void gload16(const void* g, void* l) {
    __builtin_amdgcn_global_load_lds(
        (const __attribute__((address_space(1))) unsigned int*)g,
        (__attribute__((address_space(3))) unsigned int*)l, 16, 0, 0);
}

// ---------------------------------------------------------------------------
// K1: gating. One block per token. fp32 (argmax ties must match np).
// ---------------------------------------------------------------------------
__global__ __launch_bounds__(256) void gate_kernel(const float* __restrict__ x,
                                                   const float* __restrict__ Wg,
                                                   int* __restrict__ idxbuf,
                                                   float* __restrict__ top1buf) {
    int m = blockIdx.x;
    int tid = threadIdx.x;
    int h = tid >> 4;
    int j = tid & 15;
    const float4* xr = (const float4*)(x + (size_t)m * CC);
    const float4* wr = (const float4*)(Wg + (size_t)h * CC);
    float acc = 0.f;
#pragma unroll 8
    for (int i = 0; i < CC / 4; i += 16) {
        float4 a = xr[i + j];
        float4 b = wr[i + j];
        acc += a.x * b.x + a.y * b.y + a.z * b.z + a.w * b.w;
    }
    for (int off = 8; off > 0; off >>= 1) acc += __shfl_down(acc, off, 16);
    __shared__ float logits[HH];
    if (j == 0) logits[h] = acc;
    __syncthreads();
    if (tid == 0) {
        float zmax = logits[0];
        int best = 0;
        for (int i = 1; i < HH; i++) {
            if (logits[i] > zmax) { zmax = logits[i]; best = i; }
        }
        float s = 0.f;
        for (int i = 0; i < HH; i++) s += expf(logits[i] - zmax);
        idxbuf[m] = best;
        top1buf[m] = 1.0f / s;
    }
}

// ---------------------------------------------------------------------------
// K2: fp32 -> bf16 convert (8 elems/thread, 16B stores).
// ---------------------------------------------------------------------------
__global__ __launch_bounds__(256) void convert_bf16(const float* __restrict__ src,
                                                    unsigned short* __restrict__ dst,
                                                    int n8) {
    int i = blockIdx.x * 256 + threadIdx.x;
    if (i >= n8) return;
    const float4* s4 = (const float4*)src;
    float4 a = s4[i * 2], b = s4[i * 2 + 1];
    union { unsigned short s[8]; uint4 u; } pk;
    pk.s[0] = f2bf(a.x); pk.s[1] = f2bf(a.y); pk.s[2] = f2bf(a.z); pk.s[3] = f2bf(a.w);
    pk.s[4] = f2bf(b.x); pk.s[5] = f2bf(b.y); pk.s[6] = f2bf(b.z); pk.s[7] = f2bf(b.w);
    ((uint4*)dst)[i] = pk.u;
}

// ---------------------------------------------------------------------------
// K3: qkv = xb @ wbT, bf16 MFMA GEMM (m97 structure).
// ---------------------------------------------------------------------------
__global__ __launch_bounds__(256) void qkv_gemm(const unsigned short* __restrict__ A,  // [M][2048] bf16
                                                const unsigned short* __restrict__ Bm, // [N][2048] bf16
                                                unsigned short* __restrict__ C) {      // [M][6144] bf16
    __shared__ unsigned short As[128 * BK];  // 8 KB
    __shared__ unsigned short Bs[128 * BK];  // 8 KB
    int tid = threadIdx.x;
    int wave = tid >> 6, lane = tid & 63;
    int l = lane & 15, g = lane >> 4;
    int m0 = blockIdx.y * 128, n0 = blockIdx.x * 128;
    int wr = wave >> 1, wc = wave & 1;

    f32x4 acc[4][4];
#pragma unroll
    for (int i = 0; i < 4; i++)
#pragma unroll
        for (int j = 0; j < 4; j++) acc[i][j] = (f32x4){0.f, 0.f, 0.f, 0.f};

    int srow = lane >> 2;
    int scol = (lane & 3) * 8;
    const unsigned short* aB0 = A + (size_t)(m0 + wave * 32 + srow) * 2048 + scol;
    const unsigned short* bB0 = Bm + (size_t)(n0 + wave * 32 + srow) * 2048 + scol;
    unsigned short* aL0 = &As[wave * 1024];
    unsigned short* bL0 = &Bs[wave * 1024];

    for (int k0 = 0; k0 < 2048; k0 += BK) {
        __syncthreads();
        gload16(aB0 + k0, aL0);
        gload16(aB0 + k0 + (size_t)16 * 2048, aL0 + 512);
        gload16(bB0 + k0, bL0);
        gload16(bB0 + k0 + (size_t)16 * 2048, bL0 + 512);
        __syncthreads();
        short8 af[4], bf[4];
#pragma unroll
        for (int i = 0; i < 4; i++)
            af[i] = *(const short8*)&As[(wr * 64 + i * 16 + l) * BK + g * 8];
#pragma unroll
        for (int j = 0; j < 4; j++)
            bf[j] = *(const short8*)&Bs[(wc * 64 + j * 16 + l) * BK + g * 8];
#pragma unroll
        for (int i = 0; i < 4; i++)
#pragma unroll
            for (int j = 0; j < 4; j++)
                acc[i][j] = __builtin_amdgcn_mfma_f32_16x16x32_bf16(af[i], bf[j], acc[i][j], 0, 0, 0);
    }

    const float qscale = 0.08838834764831845f;  // 1/sqrt(128)
#pragma unroll
    for (int j = 0; j < 4; j++) {
        int col = n0 + wc * 64 + j * 16 + l;
        float s = (col < 2048) ? qscale : 1.0f;
#pragma unroll
        for (int i = 0; i < 4; i++) {
            int row = m0 + wr * 64 + i * 16 + g * 4;
#pragma unroll
            for (int r = 0; r < 4; r++)
                C[(size_t)(row + r) * QKV_N + col] = f2bf(acc[i][j][r] * s);
        }
    }
}

// ---------------------------------------------------------------------------
// K4: gather selected head's k/v from qkv buffer.
// ---------------------------------------------------------------------------
__global__ __launch_bounds__(256) void kv_gather2(const unsigned short* __restrict__ qkv,
                                                  const int* __restrict__ idxb,
                                                  const float* __restrict__ top1,
                                                  unsigned short* __restrict__ kshB,
                                                  unsigned short* __restrict__ vshT) {
    __shared__ unsigned short Vs[64][136];
    int m0 = blockIdx.x * 64;
    int tid = threadIdx.x;
    int tok = tid >> 2;
    int c4 = tid & 3;
    int m = m0 + tok;
    int hs = idxb[m];
    float tv = top1[m];
    const uint4* krow = (const uint4*)(qkv + (size_t)m * QKV_N + 2048 + hs * 128);
    const uint4* vrow = (const uint4*)(qkv + (size_t)m * QKV_N + 4096 + hs * 128);
    uint4* kdst = (uint4*)(kshB + (size_t)m * HD);
#pragma unroll
    for (int u = 0; u < 4; u++) kdst[c4 * 4 + u] = krow[c4 * 4 + u];
#pragma unroll
    for (int u = 0; u < 4; u++) {
        uint4 d = vrow[c4 * 4 + u];
        unsigned short* ss = (unsigned short*)&d;
        union { unsigned short s[8]; uint4 u4; } pk;
#pragma unroll
        for (int e = 0; e < 8; e++) pk.s[e] = f2bf(bf2f(ss[e]) * tv);
        *(uint4*)&Vs[tok][(c4 * 4 + u) * 8] = pk.u4;
    }
    __syncthreads();
    int d = tid >> 1, half = tid & 1;
#pragma unroll
    for (int u = 0; u < 4; u++) {
        union { unsigned short s[8]; uint4 u4; } pk;
#pragma unroll
        for (int e = 0; e < 8; e++) pk.s[e] = Vs[half * 32 + u * 8 + e][d];
        *(uint4*)(vshT + (size_t)d * MM + m0 + half * 32 + u * 8) = pk.u4;
    }
}

// ---------------------------------------------------------------------------
// K5: MFMA bf16 flash attention, MQA head-sharing. Block = 4 waves handles
// one 16-row q-tile for 8 heads (2 heads/wave); K/V chunk staged once per
// block and reused by all 8 heads -> 264 MFMA per 32KB staging. Fixed-shift
// softmax exp(s-30); row-sum via ones-column MFMA. Longest q-tiles first.
// ---------------------------------------------------------------------------
__global__ __launch_bounds__(256) void attn_mfma(const unsigned short* __restrict__ qb,   // [M][6144] bf16, q pre-scaled
                                                 const unsigned short* __restrict__ kb,   // [M][128] bf16
                                                 const unsigned short* __restrict__ vtb,  // [128][M] bf16
                                                 float* __restrict__ y) {                 // [M][2048] fp32
    __shared__ unsigned short Ks[64][136];   // 17408 B
    __shared__ unsigned short Vt[128][72];   // 18432 B
    __shared__ unsigned short Ps[4][16][72]; //  9216 B (per-wave)

    int bid = blockIdx.x;                 // 512 blocks
    int qq = 127 - (bid >> 2);            // q-tile (16 rows), longest first
    int b  = (bid >> 1) & 1;
    int hh = bid & 1;                     // head half (0: h0..7, 1: h8..15)
    int q0 = qq * 16;
    int nch = (qq >> 2) + 1;              // 64-key chunks
    int tid = threadIdx.x;
    int wave = tid >> 6;
    int lane = tid & 63;
    int l = lane & 15;
    int g = lane >> 4;
    int h0 = hh * 8 + wave * 2;           // this wave's first head

    // Q a-frags for 2 heads (bf16, pre-scaled)
    short8 qf[2][4];
    {
        const unsigned short* qrow = qb + (size_t)(b * TT + q0 + l) * QKV_N;
#pragma unroll
        for (int hd2 = 0; hd2 < 2; hd2++)
#pragma unroll
            for (int kc = 0; kc < 4; kc++)
                qf[hd2][kc] = *(const short8*)(qrow + (h0 + hd2) * HD + kc * 32 + g * 8);
    }

    // ones-column B-frag: B[n][k] = (n==0) ? 1 : 0
    short8 onesf;
    {
        short v = (l == 0) ? (short)0x3F80 : (short)0;
#pragma unroll
        for (int e = 0; e < 8; e++) onesf[e] = v;
    }

    f32x4 o[2][8];
    f32x4 o8[2];
#pragma unroll
    for (int hd2 = 0; hd2 < 2; hd2++) {
#pragma unroll
        for (int n = 0; n < 8; n++) o[hd2][n] = (f32x4){0.f, 0.f, 0.f, 0.f};
        o8[hd2] = (f32x4){0.f, 0.f, 0.f, 0.f};
    }

    const unsigned short* kbase = kb + (size_t)b * TT * HD;
    int rbase = q0 + g * 4;

    for (int c = 0; c < nch; c++) {
        int kc0 = c * 64;
        __syncthreads();   // previous chunk's LDS reads done
        // stage K: 64 keys x 128 dims, 1024 uint4, coalesced (1KB rows)
#pragma unroll
        for (int rep = 0; rep < 4; rep++) {
            int f = tid + rep * 256;
            int row = f >> 4, c8 = f & 15;
            *(uint4*)&Ks[row][c8 * 8] =
                *(const uint4*)(kbase + (size_t)(kc0 + row) * HD + c8 * 8);
        }
        // stage Vt: 128 dims x 64 keys (transposed source, 128B segments)
#pragma unroll
        for (int rep = 0; rep < 4; rep++) {
            int f = tid + rep * 256;
            int dd = f >> 3, k8 = f & 7;
            *(uint4*)&Vt[dd][k8 * 8] =
                *(const uint4*)(vtb + (size_t)dd * MM + b * TT + kc0 + k8 * 8);
        }
        __syncthreads();
        bool diag = (c == nch - 1);

#pragma unroll
        for (int hd2 = 0; hd2 < 2; hd2++) {
            // S = Q K^T
            f32x4 st[4];
#pragma unroll
            for (int t = 0; t < 4; t++) {
                f32x4 acc = (f32x4){0.f, 0.f, 0.f, 0.f};
#pragma unroll
                for (int kc = 0; kc < 4; kc++) {
                    short8 bfr = *(const short8*)&Ks[t * 16 + l][kc * 32 + g * 8];
                    acc = __builtin_amdgcn_mfma_f32_16x16x32_bf16(qf[hd2][kc], bfr, acc, 0, 0, 0);
                }
                st[t] = acc;
            }
            if (diag) {  // causal mask, diagonal chunk only (wave-uniform)
#pragma unroll
                for (int t = 0; t < 4; t++) {
                    int key = kc0 + t * 16 + l;
#pragma unroll
                    for (int i = 0; i < 4; i++)
                        if (key > rbase + i) st[t][i] = -1e30f;
                }
            }
            // p = exp(s - 30) -> Ps (A-layout); per-wave buffer, same-wave
            // DS ordering makes write->read and head0->head1 reuse safe.
#pragma unroll
            for (int t = 0; t < 4; t++) {
#pragma unroll
                for (int i = 0; i < 4; i++) {
                    float p = __expf(st[t][i] - 30.f);
                    Ps[wave][g * 4 + i][t * 16 + l] = f2bf(p);
                }
            }
            // O += P V ; l += P (ones column)
#pragma unroll
            for (int kc2 = 0; kc2 < 2; kc2++) {
                short8 pf = *(const short8*)&Ps[wave][l][kc2 * 32 + g * 8];
#pragma unroll
                for (int n = 0; n < 8; n++) {
                    short8 vf = *(const short8*)&Vt[n * 16 + l][kc2 * 32 + g * 8];
                    o[hd2][n] = __builtin_amdgcn_mfma_f32_16x16x32_bf16(pf, vf, o[hd2][n], 0, 0, 0);
                }
                o8[hd2] = __builtin_amdgcn_mfma_f32_16x16x32_bf16(pf, onesf, o8[hd2], 0, 0, 0);
            }
        }
    }
    // epilogue: l for row g*4+i sits in lane (g*16, reg i)
#pragma unroll
    for (int hd2 = 0; hd2 < 2; hd2++) {
        float inv[4];
#pragma unroll
        for (int i = 0; i < 4; i++) {
            float lv = __shfl(o8[hd2][i], lane & 48);
            inv[i] = 1.f / lv;
        }
#pragma unroll
        for (int n = 0; n < 8; n++) {
#pragma unroll
            for (int i = 0; i < 4; i++) {
                y[(size_t)(b * TT + q0 + g * 4 + i) * CC + (h0 + hd2) * HD + n * 16 + l] =
                    o[hd2][n][i] * inv[i];
            }
        }
    }
}

// ---------------------------------------------------------------------------
// Launcher. Workspace (~94.5 MB).
// ---------------------------------------------------------------------------
extern "C" void kernel_launch(void* const* d_in, const int* in_sizes, int n_in,
                              void* d_out, int out_size, void* d_ws, size_t ws_size,
                              hipStream_t stream) {
    (void)in_sizes; (void)n_in; (void)out_size; (void)ws_size;
    const float* x    = (const float*)d_in[0];
    const float* Wg   = (const float*)d_in[1];
    const float* Wqkv = (const float*)d_in[2];
    float* y = (float*)d_out;

    unsigned short* xb   = (unsigned short*)d_ws;
    unsigned short* wb   = xb + (size_t)MM * CC;
    unsigned short* qkvB = wb + (size_t)QKV_N * CC;
    unsigned short* kshB = qkvB + (size_t)MM * QKV_N;
    unsigned short* vshT = kshB + (size_t)MM * HD;
    float* top1 = (float*)(vshT + (size_t)HD * MM);
    int*   idxb = (int*)(top1 + MM);

    gate_kernel<<<MM, 256, 0, stream>>>(x, Wg, idxb, top1);
    convert_bf16<<<(MM * CC / 8 + 255) / 256, 256, 0, stream>>>(x, xb, MM * CC / 8);
    convert_bf16<<<(QKV_N * CC / 8 + 255) / 256, 256, 0, stream>>>(Wqkv, wb, QKV_N * CC / 8);
    qkv_gemm<<<dim3(QKV_N / 128, MM / 128), 256, 0, stream>>>(xb, wb, qkvB);
    kv_gather2<<<MM / 64, 256, 0, stream>>>(qkvB, idxb, top1, kshB, vshT);
    attn_mfma<<<512, 256, 0, stream>>>(qkvB, kshB, vshT, y);
}